// Round 3
// baseline (296.316 us; speedup 1.0000x reference)
//
#include <hip/hip_runtime.h>

// Problem constants (from reference): E=1024, H=16, D=64, B=32, S=1024.
// ALGEBRA: softmax over a length-1 key axis == 1.0 exactly, so attention
// collapses: attn_out[b,:] = Wo @ (Wv @ (W_heat @ heat[b] + b_heat) + bv) + bo
// (independent of s; the img projection / Q / K path is dead code).
// Final: out[b,s,:] = LayerNorm(img_feat[b,s,:] + a[b,:]) * gamma + beta.
// All tensors fp32. Vanilla HIP types / plain loads only (rounds 1-2 hit
// infra failures; this round hedges out the custom-vector/nontemporal paths).

#define E_DIM 1024
#define B_DIM 32
#define S_DIM 1024

// ---- GEMV stage: y[b,e] = dot(W[e,:], x[b,:]) + bias[e] -------------------
// Each block stages 8 batches of x in LDS (32 KiB) and each wave reads its
// W row ONCE, dotting it against all 8 staged x vectors. W traffic per GEMV:
// 256 MiB (one-wave-per-output) -> 16 MiB.
// Grid: 1024 blocks = 256 row-groups (4 rows each, 1/wave) x 4 batch-quarters.
__global__ __launch_bounds__(256) void gemv_xlds(
        const float* __restrict__ W,    // [E,E] row-major
        const float* __restrict__ bias, // [E]
        const float* __restrict__ x,    // [B,E]
        float* __restrict__ y) {        // [B,E]
    __shared__ float4 xs[8 * 256];       // 8 batches x 1024 f32 = 32 KiB
    const int t = threadIdx.x;
    const int rg = blockIdx.x & 255;     // row group -> rows [rg*4, rg*4+4)
    const int bq = blockIdx.x >> 8;      // batch quarter -> batches [bq*8, ..+8)

    // Stage x[bq*8 .. bq*8+8, :] into LDS, coalesced float4 copies.
    const float4* x4 = reinterpret_cast<const float4*>(x) + (size_t)bq * 8 * 256;
    #pragma unroll
    for (int i = 0; i < 8; ++i)
        xs[i * 256 + t] = x4[i * 256 + t];
    __syncthreads();

    const int wave = t >> 6;
    const int lane = t & 63;
    const int e = rg * 4 + wave;

    // W row e: lane holds float4 slots {p*64+lane}, p=0..3 (coalesced).
    const float4* w4 = reinterpret_cast<const float4*>(W + (size_t)e * E_DIM);
    float4 w0 = w4[lane];
    float4 w1 = w4[64 + lane];
    float4 w2 = w4[128 + lane];
    float4 w3 = w4[192 + lane];

    float acc[8];
    #pragma unroll
    for (int i = 0; i < 8; ++i) acc[i] = 0.f;

    #pragma unroll
    for (int i = 0; i < 8; ++i) {
        float4 a0 = xs[i * 256 + lane];
        float4 a1 = xs[i * 256 + 64 + lane];
        float4 a2 = xs[i * 256 + 128 + lane];
        float4 a3 = xs[i * 256 + 192 + lane];
        float r = w0.x * a0.x + w0.y * a0.y + w0.z * a0.z + w0.w * a0.w;
        r += w1.x * a1.x + w1.y * a1.y + w1.z * a1.z + w1.w * a1.w;
        r += w2.x * a2.x + w2.y * a2.y + w2.z * a2.z + w2.w * a2.w;
        r += w3.x * a3.x + w3.y * a3.y + w3.z * a3.z + w3.w * a3.w;
        acc[i] = r;
    }

    // Butterfly so every lane holds the full 1024-dot for each staged batch.
    #pragma unroll
    for (int off = 32; off; off >>= 1) {
        #pragma unroll
        for (int i = 0; i < 8; ++i)
            acc[i] += __shfl_xor(acc[i], off, 64);
    }

    if (lane == 0) {
        const float bs = bias[e];
        #pragma unroll
        for (int i = 0; i < 8; ++i)
            y[(size_t)(bq * 8 + i) * E_DIM + e] = acc[i] + bs;
    }
}

// ---- Fused residual-add + LayerNorm ---------------------------------------
// One WAVE per row; no LDS, no __syncthreads -- the 64-lane __shfl_xor
// butterfly leaves mu/rstd in every lane. Each wave handles 4 CONSECUTIVE
// rows of the same batch, so a[b,:], gamma, beta are loaded once per wave
// and held in registers (3 x 16 VGPRs).
__global__ __launch_bounds__(256) void resid_ln(
        const float* __restrict__ img,   // [B,S,E]
        const float* __restrict__ a,     // [B,E]
        const float* __restrict__ gamma, // [E]
        const float* __restrict__ beta,  // [E]
        float* __restrict__ out) {       // [B,S,E]
    const int t = threadIdx.x;
    const int wave = t >> 6;
    const int lane = t & 63;
    const int row0 = blockIdx.x * 16 + wave * 4;   // 16 rows/block, 4/wave
    const int b = row0 >> 10;                      // S=1024 rows/batch; 16|1024
                                                   // so no block straddles.

    const float4* g4  = reinterpret_cast<const float4*>(gamma);
    const float4* be4 = reinterpret_cast<const float4*>(beta);
    const float4* a4  = reinterpret_cast<const float4*>(a + (size_t)b * E_DIM);
    float4 gv[4], bv[4], av[4];
    #pragma unroll
    for (int p = 0; p < 4; ++p) {
        gv[p] = g4[p * 64 + lane];
        bv[p] = be4[p * 64 + lane];
        av[p] = a4[p * 64 + lane];
    }

    #pragma unroll
    for (int r = 0; r < 4; ++r) {
        const size_t base = (size_t)(row0 + r) * E_DIM;
        const float4* i4 = reinterpret_cast<const float4*>(img + base);

        float4 x[4];
        float s = 0.f, q = 0.f;
        #pragma unroll
        for (int p = 0; p < 4; ++p) {
            float4 iv = i4[p * 64 + lane];
            x[p].x = iv.x + av[p].x;
            x[p].y = iv.y + av[p].y;
            x[p].z = iv.z + av[p].z;
            x[p].w = iv.w + av[p].w;
            s += x[p].x + x[p].y + x[p].z + x[p].w;
            q += x[p].x * x[p].x + x[p].y * x[p].y
               + x[p].z * x[p].z + x[p].w * x[p].w;
        }

        #pragma unroll
        for (int off = 32; off; off >>= 1) {
            s += __shfl_xor(s, off, 64);
            q += __shfl_xor(q, off, 64);
        }
        const float mu   = s * (1.0f / E_DIM);
        const float rstd = rsqrtf(q * (1.0f / E_DIM) - mu * mu + 1e-5f);

        float4* o4 = reinterpret_cast<float4*>(out + base);
        #pragma unroll
        for (int p = 0; p < 4; ++p) {
            float4 ov;
            ov.x = (x[p].x - mu) * rstd * gv[p].x + bv[p].x;
            ov.y = (x[p].y - mu) * rstd * gv[p].y + bv[p].y;
            ov.z = (x[p].z - mu) * rstd * gv[p].z + bv[p].z;
            ov.w = (x[p].w - mu) * rstd * gv[p].w + bv[p].w;
            o4[p * 64 + lane] = ov;
        }
    }
}

extern "C" void kernel_launch(void* const* d_in, const int* in_sizes, int n_in,
                              void* d_out, int out_size, void* d_ws, size_t ws_size,
                              hipStream_t stream) {
    // setup_inputs order:
    // 0 img_feat [B,S,E], 1 heat_feat [B,E], 2 W_img, 3 b_img, 4 W_heat, 5 b_heat,
    // 6 Wq, 7 bq, 8 Wk, 9 bk, 10 Wv, 11 bv, 12 Wo, 13 bo, 14 gamma, 15 beta
    const float* heat   = (const float*)d_in[1];
    const float* W_heat = (const float*)d_in[4];
    const float* b_heat = (const float*)d_in[5];
    const float* Wv     = (const float*)d_in[10];
    const float* bvv    = (const float*)d_in[11];
    const float* Wo     = (const float*)d_in[12];
    const float* bo     = (const float*)d_in[13];
    const float* img    = (const float*)d_in[0];
    const float* gamma  = (const float*)d_in[14];
    const float* beta   = (const float*)d_in[15];
    float* out = (float*)d_out;

    // Workspace: 3 fp32 [B,E] buffers = 384 KiB.
    float* ws = (float*)d_ws;
    float* tt = ws;                      // W_heat stage
    float* vv = ws + B_DIM * E_DIM;      // Wv stage
    float* aa = ws + 2 * B_DIM * E_DIM;  // Wo stage (attn_out rows)

    // 1024 blocks = 256 row-groups x 4 batch-quarters.
    gemv_xlds<<<1024, 256, 0, stream>>>(W_heat, b_heat, heat, tt);
    gemv_xlds<<<1024, 256, 0, stream>>>(Wv, bvv, tt, vv);
    gemv_xlds<<<1024, 256, 0, stream>>>(Wo, bo, vv, aa);

    // 2048 blocks x 256 thr; 16 rows/block (4 rows per wave).
    resid_ln<<<(B_DIM * S_DIM) / 16, 256, 0, stream>>>(img, aa, gamma, beta, out);
}

// Round 4
// 289.920 us; speedup vs baseline: 1.0221x; 1.0221x over previous
//
#include <hip/hip_runtime.h>

// Problem constants (from reference): E=1024, H=16, D=64, B=32, S=1024.
// ALGEBRA: softmax over a length-1 key axis == 1.0 exactly, so attention
// collapses: attn_out[b,:] = Wo @ (Wv @ (W_heat @ heat[b] + b_heat) + bv) + bo
// (independent of s; the img projection / Q / K path is dead code).
// Final: out[b,s,:] = LayerNorm(img_feat[b,s,:] + a[b,:]) * gamma + beta.
// All tensors fp32. Vanilla HIP types / plain loads only.

#define E_DIM 1024
#define B_DIM 32
#define S_DIM 1024

// ---- GEMV stage: y[b,e] = dot(W[e,:], x[b,:]) + bias[e] -------------------
// (unchanged from the passing round-3 version)
// Each block stages 8 batches of x in LDS (32 KiB) and each wave reads its
// W row ONCE, dotting it against all 8 staged x vectors. W traffic per GEMV:
// 256 MiB (one-wave-per-output) -> 16 MiB.
// Grid: 1024 blocks = 256 row-groups (4 rows each, 1/wave) x 4 batch-quarters.
__global__ __launch_bounds__(256) void gemv_xlds(
        const float* __restrict__ W,    // [E,E] row-major
        const float* __restrict__ bias, // [E]
        const float* __restrict__ x,    // [B,E]
        float* __restrict__ y) {        // [B,E]
    __shared__ float4 xs[8 * 256];       // 8 batches x 1024 f32 = 32 KiB
    const int t = threadIdx.x;
    const int rg = blockIdx.x & 255;     // row group -> rows [rg*4, rg*4+4)
    const int bq = blockIdx.x >> 8;      // batch quarter -> batches [bq*8, ..+8)

    const float4* x4 = reinterpret_cast<const float4*>(x) + (size_t)bq * 8 * 256;
    #pragma unroll
    for (int i = 0; i < 8; ++i)
        xs[i * 256 + t] = x4[i * 256 + t];
    __syncthreads();

    const int wave = t >> 6;
    const int lane = t & 63;
    const int e = rg * 4 + wave;

    const float4* w4 = reinterpret_cast<const float4*>(W + (size_t)e * E_DIM);
    float4 w0 = w4[lane];
    float4 w1 = w4[64 + lane];
    float4 w2 = w4[128 + lane];
    float4 w3 = w4[192 + lane];

    float acc[8];
    #pragma unroll
    for (int i = 0; i < 8; ++i) acc[i] = 0.f;

    #pragma unroll
    for (int i = 0; i < 8; ++i) {
        float4 a0 = xs[i * 256 + lane];
        float4 a1 = xs[i * 256 + 64 + lane];
        float4 a2 = xs[i * 256 + 128 + lane];
        float4 a3 = xs[i * 256 + 192 + lane];
        float r = w0.x * a0.x + w0.y * a0.y + w0.z * a0.z + w0.w * a0.w;
        r += w1.x * a1.x + w1.y * a1.y + w1.z * a1.z + w1.w * a1.w;
        r += w2.x * a2.x + w2.y * a2.y + w2.z * a2.z + w2.w * a2.w;
        r += w3.x * a3.x + w3.y * a3.y + w3.z * a3.z + w3.w * a3.w;
        acc[i] = r;
    }

    #pragma unroll
    for (int off = 32; off; off >>= 1) {
        #pragma unroll
        for (int i = 0; i < 8; ++i)
            acc[i] += __shfl_xor(acc[i], off, 64);
    }

    if (lane == 0) {
        const float bs = bias[e];
        #pragma unroll
        for (int i = 0; i < 8; ++i)
            y[(size_t)(bq * 8 + i) * E_DIM + e] = acc[i] + bs;
    }
}

// ---- Fused residual-add + LayerNorm, software-pipelined -------------------
// Round-3 profile: 81 us @ 2.5 TB/s (31% peak), VALUBusy 6.6%, VGPR 56.
// Diagnosis: each wave ran its rows serially -- 4 loads, dependent 12-op
// shfl butterfly (~500 cyc), store, repeat -- so <=1 row (4 KiB) in flight
// per wave; latency exposed. Fix: 8 rows/wave with a 3-buffer rotation that
// issues row r+2's loads BEFORE reducing row r => 2 rows (8 KiB) always in
// flight per wave, independent of occupancy. a/gamma/beta register-cached
// (whole wave stays in one batch: 32 | 1024).
__global__ __launch_bounds__(256) void resid_ln(
        const float* __restrict__ img,   // [B,S,E]
        const float* __restrict__ a,     // [B,E]
        const float* __restrict__ gamma, // [E]
        const float* __restrict__ beta,  // [E]
        float* __restrict__ out) {       // [B,S,E]
    const int t = threadIdx.x;
    const int wave = t >> 6;
    const int lane = t & 63;
    const int row0 = blockIdx.x * 32 + wave * 8;   // 32 rows/block, 8/wave
    const int b = row0 >> 10;                      // 32 | 1024: no straddle

    const float4* g4  = reinterpret_cast<const float4*>(gamma);
    const float4* be4 = reinterpret_cast<const float4*>(beta);
    const float4* a4  = reinterpret_cast<const float4*>(a + (size_t)b * E_DIM);
    float4 gv[4], bv[4], av[4];
    #pragma unroll
    for (int p = 0; p < 4; ++p) {
        gv[p] = g4[p * 64 + lane];
        bv[p] = be4[p * 64 + lane];
        av[p] = a4[p * 64 + lane];
    }

    float4 xA[4], xB[4], xC[4];

    // Pure loads (no arithmetic) so the compiler can use counted vmcnt.
#define LN_LOAD(X, rr)                                                        \
    {                                                                         \
        const float4* i4 =                                                    \
            reinterpret_cast<const float4*>(img + (size_t)(row0 + (rr)) * E_DIM); \
        X[0] = i4[lane];                                                      \
        X[1] = i4[64 + lane];                                                 \
        X[2] = i4[128 + lane];                                                \
        X[3] = i4[192 + lane];                                                \
    }

#define LN_PROC(X, rr)                                                        \
    {                                                                         \
        float4 y[4];                                                          \
        float s = 0.f, q = 0.f;                                               \
        _Pragma("unroll")                                                     \
        for (int p = 0; p < 4; ++p) {                                         \
            y[p].x = X[p].x + av[p].x;                                        \
            y[p].y = X[p].y + av[p].y;                                        \
            y[p].z = X[p].z + av[p].z;                                        \
            y[p].w = X[p].w + av[p].w;                                        \
            s += y[p].x + y[p].y + y[p].z + y[p].w;                           \
            q += y[p].x * y[p].x + y[p].y * y[p].y                            \
               + y[p].z * y[p].z + y[p].w * y[p].w;                           \
        }                                                                     \
        _Pragma("unroll")                                                     \
        for (int off = 32; off; off >>= 1) {                                  \
            s += __shfl_xor(s, off, 64);                                      \
            q += __shfl_xor(q, off, 64);                                      \
        }                                                                     \
        const float mu   = s * (1.0f / E_DIM);                                \
        const float rstd = rsqrtf(q * (1.0f / E_DIM) - mu * mu + 1e-5f);      \
        float4* o4 =                                                          \
            reinterpret_cast<float4*>(out + (size_t)(row0 + (rr)) * E_DIM);   \
        _Pragma("unroll")                                                     \
        for (int p = 0; p < 4; ++p) {                                         \
            float4 ov;                                                        \
            ov.x = (y[p].x - mu) * rstd * gv[p].x + bv[p].x;                  \
            ov.y = (y[p].y - mu) * rstd * gv[p].y + bv[p].y;                  \
            ov.z = (y[p].z - mu) * rstd * gv[p].z + bv[p].z;                  \
            ov.w = (y[p].w - mu) * rstd * gv[p].w + bv[p].w;                  \
            o4[p * 64 + lane] = ov;                                           \
        }                                                                     \
    }

    // 3-buffer rotation, 2 rows in flight ahead of each reduce. All indices
    // compile-time constant (rule #20: no runtime-indexed register arrays).
    LN_LOAD(xA, 0)
    LN_LOAD(xB, 1)
    LN_LOAD(xC, 2) LN_PROC(xA, 0)
    LN_LOAD(xA, 3) LN_PROC(xB, 1)
    LN_LOAD(xB, 4) LN_PROC(xC, 2)
    LN_LOAD(xC, 5) LN_PROC(xA, 3)
    LN_LOAD(xA, 6) LN_PROC(xB, 4)
    LN_LOAD(xB, 7) LN_PROC(xC, 5)
    LN_PROC(xA, 6)
    LN_PROC(xB, 7)

#undef LN_LOAD
#undef LN_PROC
}

extern "C" void kernel_launch(void* const* d_in, const int* in_sizes, int n_in,
                              void* d_out, int out_size, void* d_ws, size_t ws_size,
                              hipStream_t stream) {
    // setup_inputs order:
    // 0 img_feat [B,S,E], 1 heat_feat [B,E], 2 W_img, 3 b_img, 4 W_heat, 5 b_heat,
    // 6 Wq, 7 bq, 8 Wk, 9 bk, 10 Wv, 11 bv, 12 Wo, 13 bo, 14 gamma, 15 beta
    const float* heat   = (const float*)d_in[1];
    const float* W_heat = (const float*)d_in[4];
    const float* b_heat = (const float*)d_in[5];
    const float* Wv     = (const float*)d_in[10];
    const float* bvv    = (const float*)d_in[11];
    const float* Wo     = (const float*)d_in[12];
    const float* bo     = (const float*)d_in[13];
    const float* img    = (const float*)d_in[0];
    const float* gamma  = (const float*)d_in[14];
    const float* beta   = (const float*)d_in[15];
    float* out = (float*)d_out;

    // Workspace: 3 fp32 [B,E] buffers = 384 KiB.
    float* ws = (float*)d_ws;
    float* tt = ws;                      // W_heat stage
    float* vv = ws + B_DIM * E_DIM;      // Wv stage
    float* aa = ws + 2 * B_DIM * E_DIM;  // Wo stage (attn_out rows)

    // 1024 blocks = 256 row-groups x 4 batch-quarters.
    gemv_xlds<<<1024, 256, 0, stream>>>(W_heat, b_heat, heat, tt);
    gemv_xlds<<<1024, 256, 0, stream>>>(Wv, bvv, tt, vv);
    gemv_xlds<<<1024, 256, 0, stream>>>(Wo, bo, vv, aa);

    // 1024 blocks x 256 thr; 32 rows/block (8 rows per wave, pipelined).
    resid_ln<<<(B_DIM * S_DIM) / 32, 256, 0, stream>>>(img, aa, gamma, beta, out);
}